// Round 2
// baseline (818.799 us; speedup 1.0000x reference)
//
#include <hip/hip_runtime.h>
#include <hip/hip_bf16.h>

typedef __attribute__((ext_vector_type(8))) short bf16x8;
typedef __attribute__((ext_vector_type(4))) float f32x4;
typedef __attribute__((ext_vector_type(8))) unsigned short ushort8;

__device__ __forceinline__ float bf2f(unsigned short u) {
  union { unsigned int i; float f; } v; v.i = ((unsigned int)u) << 16; return v.f;
}
__device__ __forceinline__ unsigned short f2bf(float f) {
  __hip_bfloat16 h = __float2bfloat16(f);
  unsigned short u; __builtin_memcpy(&u, &h, 2); return u;
}

// ---------------------------------------------------------------------------
// Kernel P: convert qkv_w (384x128) and proj_w (128x128) fp32 -> bf16 in ws
// ---------------------------------------------------------------------------
__global__ void k_prep(const float* __restrict__ qkvw, const float* __restrict__ projw,
                       unsigned short* __restrict__ qkvw_bf,
                       unsigned short* __restrict__ projw_bf) {
  int t = blockIdx.x * 256 + threadIdx.x;   // 16384 threads x 4 elements
  int i = t * 4;
  const float* src;
  unsigned short* dst;
  int idx;
  if (i < 49152) { src = qkvw; dst = qkvw_bf; idx = i; }
  else           { src = projw; dst = projw_bf; idx = i - 49152; }
  float4 v = *(const float4*)(src + idx);
  union { unsigned short u[4]; uint2 v2; } o;
  o.u[0] = f2bf(v.x); o.u[1] = f2bf(v.y); o.u[2] = f2bf(v.z); o.u[3] = f2bf(v.w);
  *(uint2*)(dst + idx) = o.v2;
}

// ---------------------------------------------------------------------------
// Kernel 0: bias2d[h*2401 + row*49+col] = bias_table[rel_index[row*49+col]][h]
// ---------------------------------------------------------------------------
__global__ void k_bias(const float* __restrict__ bt,
                       const int* __restrict__ ri,
                       float* __restrict__ b2d) {
  int t = blockIdx.x * 256 + threadIdx.x;
  if (t < 9604) {
    int hq = t / 2401;
    int rc = t - hq * 2401;
    b2d[t] = bt[ri[rc] * 4 + hq];
  }
}

// ---------------------------------------------------------------------------
// Kernel 1: LayerNorm over C + cyclic shift (-3,-3) + window partition
// x (B,C,H,W) fp32 -> xw (8192 windows, 49 tokens, 128 ch) bf16
// ---------------------------------------------------------------------------
__global__ __launch_bounds__(256, 4) void k_ln(const float* __restrict__ x,
                                               const float* __restrict__ nw,
                                               const float* __restrict__ nb,
                                               unsigned short* __restrict__ xw) {
  int p = blockIdx.x * 256 + threadIdx.x;   // 0 .. 401407 (exact)
  int b = p / 12544;
  int r = p - b * 12544;
  int hh = r / 112;
  int wp = r - hh * 112;
  const float* bx = x + (size_t)b * 1605632 + r;  // b*C*H*W + h*W + w

  float sum = 0.f, ss = 0.f;
  #pragma unroll 16
  for (int c = 0; c < 128; ++c) {
    float v = bx[(size_t)c * 12544];
    sum += v; ss += v * v;
  }
  float mu = sum * 0.0078125f;
  float var = ss * 0.0078125f - mu * mu;
  float rstd = rsqrtf(var + 1e-5f);

  // destination (shifted coords): h' = (hh-3) mod 112
  int h2 = hh + 109; if (h2 >= 112) h2 -= 112;
  int w2 = wp + 109; if (w2 >= 112) w2 -= 112;
  int wh = h2 / 7, ii = h2 - wh * 7;
  int ww = w2 / 7, jj = w2 - ww * 7;
  int winl = (b * 16 + wh) * 16 + ww;
  unsigned short* dst = xw + ((size_t)winl * 49 + ii * 7 + jj) * 128;

  #pragma unroll
  for (int g = 0; g < 4; ++g) {
    unsigned int pk[16];
    #pragma unroll
    for (int q = 0; q < 16; ++q) {
      int c = g * 32 + 2 * q;
      float v0 = bx[(size_t)c * 12544];
      float v1 = bx[(size_t)(c + 1) * 12544];
      float y0 = (v0 - mu) * rstd * nw[c]     + nb[c];
      float y1 = (v1 - mu) * rstd * nw[c + 1] + nb[c + 1];
      pk[q] = (unsigned int)f2bf(y0) | ((unsigned int)f2bf(y1) << 16);
    }
    uint4* d4 = (uint4*)(dst + g * 32);
    #pragma unroll
    for (int k = 0; k < 4; ++k)
      d4[k] = make_uint4(pk[4 * k], pk[4 * k + 1], pk[4 * k + 2], pk[4 * k + 3]);
  }
}

// ---------------------------------------------------------------------------
// Kernel 2: fused window attention. 1 block = 1 window, wave h = head h.
// LDS layout (59392 B total), phase-overlaid:
//   head block hb(h) = h*14848:
//     Q [64][40] bf16 @ hb+0     (later P [64][72] @ hb+0, later O [64][40] @ hb+0)
//     K [64][40] bf16 @ hb+5120
//     V^T [32][72] bf16 @ hb+10240
//   X staging [64][136] bf16 @ 0 (dead after xf loads; overlaps head blocks 0/1)
// ---------------------------------------------------------------------------
__global__ __launch_bounds__(256, 2) void k_attn(
    const unsigned short* __restrict__ xw,
    const unsigned short* __restrict__ qkvw,
    const float* __restrict__ qkvb,
    const unsigned short* __restrict__ projw,
    const float* __restrict__ projb,
    const float* __restrict__ b2d,
    const float* __restrict__ amask,
    unsigned short* __restrict__ yw) {
  __shared__ __attribute__((aligned(16))) char smem[59392];
  const int tid  = threadIdx.x;
  const int lane = tid & 63;
  const int h    = tid >> 6;
  const int m15  = lane & 15;
  const int quad = lane >> 4;
  const int win  = blockIdx.x;
  const int b    = win >> 8;
  const int wrem = win & 255;
  const int wh   = wrem >> 4;
  const int ww   = wrem & 15;
  const f32x4 fz = {0.f, 0.f, 0.f, 0.f};

  // ---- stage X window (49x128, pad to 64 rows with zeros), stride 136 ----
  {
    const uint4* gsrc = (const uint4*)(xw + (size_t)win * 6272);
    #pragma unroll
    for (int it = 0; it < 4; ++it) {
      int cc = tid + it * 256;                 // 16B chunk index, 0..1023
      int row = cc >> 4, col = cc & 15;
      uint4 v = make_uint4(0u, 0u, 0u, 0u);
      if (cc < 784) v = gsrc[cc];
      *(uint4*)(smem + row * 272 + col * 16) = v;
    }
  }
  __syncthreads();

  // ---- A-fragments of X (each wave loads all; X LDS dead afterwards) ----
  bf16x8 xf[4][4];
  #pragma unroll
  for (int mt = 0; mt < 4; ++mt)
    #pragma unroll
    for (int kt = 0; kt < 4; ++kt)
      xf[mt][kt] = *(const bf16x8*)(smem + (mt * 16 + m15) * 272 + kt * 64 + quad * 16);
  __syncthreads();

  char* const hb  = smem + h * 14848;
  char* const qpb = hb;           // Q, then P, then O
  char* const kpb = hb + 5120;    // K
  char* const vpb = hb + 10240;   // V^T

  // ---- QKV GEMM: wave h computes head h's Q,K,V (6 of 24 n-tiles) ----
  #pragma unroll
  for (int g = 0; g < 3; ++g) {            // 0:Q 1:K 2:V
    #pragma unroll
    for (int sp = 0; sp < 2; ++sp) {
      int nt = g * 8 + 2 * h + sp;
      int f = nt * 16 + m15;               // feature 0..383
      bf16x8 wfr[4];
      #pragma unroll
      for (int kt = 0; kt < 4; ++kt)       // B-frag straight from global row
        wfr[kt] = *(const bf16x8*)(qkvw + f * 128 + kt * 32 + quad * 8);
      float bias = qkvb[f];
      int dsub = sp * 16 + m15;            // dim within head, 0..31
      #pragma unroll
      for (int mt = 0; mt < 4; ++mt) {
        f32x4 acc = fz;
        #pragma unroll
        for (int kt = 0; kt < 4; ++kt)
          acc = __builtin_amdgcn_mfma_f32_16x16x32_bf16(xf[mt][kt], wfr[kt], acc, 0, 0, 0);
        #pragma unroll
        for (int rr = 0; rr < 4; ++rr) {
          int token = mt * 16 + quad * 4 + rr;
          unsigned short val = f2bf(acc[rr] + bias);
          if (g == 0)      *(unsigned short*)(qpb + token * 80 + dsub * 2) = val;
          else if (g == 1) *(unsigned short*)(kpb + token * 80 + dsub * 2) = val;
          else             *(unsigned short*)(vpb + dsub * 144 + token * 2) = val;
        }
      }
    }
  }

  // ---- S = Q K^T (per head, K-dim = 32 = one MFMA step) ----
  bf16x8 qf[4], kf[4];
  #pragma unroll
  for (int t = 0; t < 4; ++t) {
    qf[t] = *(const bf16x8*)(qpb + (t * 16 + m15) * 80 + quad * 16);
    kf[t] = *(const bf16x8*)(kpb + (t * 16 + m15) * 80 + quad * 16);
  }
  f32x4 sacc[4][4];
  #pragma unroll
  for (int mt = 0; mt < 4; ++mt)
    #pragma unroll
    for (int nt = 0; nt < 4; ++nt)
      sacc[mt][nt] = __builtin_amdgcn_mfma_f32_16x16x32_bf16(qf[mt], kf[nt], fz, 0, 0, 0);

  // ---- scale + bias + mask + softmax; P (bf16) overlays Q/K region ----
  const float* bp = b2d + h * 2401;
  const float* mp = amask + wrem * 2401;
  #pragma unroll
  for (int mt = 0; mt < 4; ++mt) {
    #pragma unroll
    for (int rr = 0; rr < 4; ++rr) {
      int row = mt * 16 + quad * 4 + rr;
      int rb = row * 49;
      float sv[4];
      #pragma unroll
      for (int nt = 0; nt < 4; ++nt) {
        int col = nt * 16 + m15;
        float s = -1e30f;
        if (row < 49 && col < 49)
          s = sacc[mt][nt][rr] * 0.17677669529663687f + bp[rb + col] + mp[rb + col];
        sv[nt] = s;
      }
      float mx = fmaxf(fmaxf(sv[0], sv[1]), fmaxf(sv[2], sv[3]));
      mx = fmaxf(mx, __shfl_xor(mx, 1));
      mx = fmaxf(mx, __shfl_xor(mx, 2));
      mx = fmaxf(mx, __shfl_xor(mx, 4));
      mx = fmaxf(mx, __shfl_xor(mx, 8));
      float pv[4]; float sum = 0.f;
      #pragma unroll
      for (int nt = 0; nt < 4; ++nt) { pv[nt] = __expf(sv[nt] - mx); sum += pv[nt]; }
      sum += __shfl_xor(sum, 1);
      sum += __shfl_xor(sum, 2);
      sum += __shfl_xor(sum, 4);
      sum += __shfl_xor(sum, 8);
      float rinv = 1.0f / sum;
      #pragma unroll
      for (int nt = 0; nt < 4; ++nt)
        *(unsigned short*)(qpb + row * 144 + (nt * 16 + m15) * 2) = f2bf(pv[nt] * rinv);
    }
  }

  // ---- O = P V ----
  f32x4 oacc[4][2];
  #pragma unroll
  for (int mt = 0; mt < 4; ++mt) {
    #pragma unroll
    for (int nt = 0; nt < 2; ++nt) {
      f32x4 acc = fz;
      #pragma unroll
      for (int kt = 0; kt < 2; ++kt) {
        bf16x8 pf = *(const bf16x8*)(qpb + (mt * 16 + m15) * 144 + kt * 64 + quad * 16);
        bf16x8 vf = *(const bf16x8*)(vpb + (nt * 16 + m15) * 144 + kt * 64 + quad * 16);
        acc = __builtin_amdgcn_mfma_f32_16x16x32_bf16(pf, vf, acc, 0, 0, 0);
      }
      oacc[mt][nt] = acc;
    }
  }
  // O (per-head [64 tokens][32 dims], stride 40) overlays own P/Q region
  #pragma unroll
  for (int mt = 0; mt < 4; ++mt)
    #pragma unroll
    for (int nt = 0; nt < 2; ++nt)
      #pragma unroll
      for (int rr = 0; rr < 4; ++rr) {
        int token = mt * 16 + quad * 4 + rr;
        *(unsigned short*)(qpb + token * 80 + (nt * 16 + m15) * 2) = f2bf(oacc[mt][nt][rr]);
      }
  __syncthreads();

  // ---- proj: Y = O @ proj_w^T + proj_b; A-frags span all 4 head chunks ----
  bf16x8 of[4][4];
  #pragma unroll
  for (int mt = 0; mt < 4; ++mt)
    #pragma unroll
    for (int kt = 0; kt < 4; ++kt)   // head chunk kt holds feats kt*32..+32
      of[mt][kt] = *(const bf16x8*)(smem + kt * 14848 + (mt * 16 + m15) * 80 + quad * 16);

  const size_t obase = (size_t)b * 1605632;
  #pragma unroll
  for (int sp = 0; sp < 2; ++sp) {
    int cout = (2 * h + sp) * 16 + m15;
    bf16x8 wf[4];
    #pragma unroll
    for (int kt = 0; kt < 4; ++kt)
      wf[kt] = *(const bf16x8*)(projw + cout * 128 + kt * 32 + quad * 8);
    float pb = projb[cout];
    #pragma unroll
    for (int mt = 0; mt < 4; ++mt) {
      f32x4 acc = fz;
      #pragma unroll
      for (int kt = 0; kt < 4; ++kt)
        acc = __builtin_amdgcn_mfma_f32_16x16x32_bf16(of[mt][kt], wf[kt], acc, 0, 0, 0);
      #pragma unroll
      for (int rr = 0; rr < 4; ++rr) {
        int token = mt * 16 + quad * 4 + rr;
        if (token < 49) {
          int ii = token / 7, jj = token - ii * 7;
          int gh = wh * 7 + ii + 3; if (gh >= 112) gh -= 112;   // reverse roll
          int gw = ww * 7 + jj + 3; if (gw >= 112) gw -= 112;
          yw[obase + ((size_t)(gh * 112 + gw)) * 128 + cout] = f2bf(acc[rr] + pb);
        }
      }
    }
  }
}

// ---------------------------------------------------------------------------
// Kernel 3: yws (B,H,W,C) bf16 + shortcut x (B,C,H,W) fp32 -> out fp32 NCHW
// ---------------------------------------------------------------------------
__global__ __launch_bounds__(256) void k_out(const unsigned short* __restrict__ yws,
                                             const float* __restrict__ x,
                                             float* __restrict__ out) {
  __shared__ unsigned short T[128 * 128];  // [c][w], w padded to 128
  int tid = threadIdx.x;
  int bid = blockIdx.x;
  int b = bid / 112;
  int hh = bid - b * 112;
  const unsigned short* src = yws + (size_t)(b * 112 + hh) * 14336;
  #pragma unroll
  for (int it = 0; it < 7; ++it) {
    int cc = tid + it * 256;                 // 1792 chunks of 8 channels
    int w = cc >> 4, c8 = (cc & 15) * 8;
    ushort8 v = *(const ushort8*)(src + w * 128 + c8);
    #pragma unroll
    for (int k = 0; k < 8; ++k) T[(c8 + k) * 128 + w] = v[k];
  }
  __syncthreads();
  int c = tid >> 1, half = tid & 1;
  size_t rowoff = ((size_t)(b * 128 + c) * 112 + hh) * 112;
  const float* xr = x + rowoff;
  float* outr = out + rowoff;
  #pragma unroll
  for (int s2 = 0; s2 < 7; ++s2) {
    int w = half * 56 + s2 * 8;
    ushort8 yv = *(const ushort8*)(T + c * 128 + w);
    float4 xa = *(const float4*)(xr + w);
    float4 xb = *(const float4*)(xr + w + 4);
    float4 oa, ob;
    oa.x = bf2f(yv[0]) + xa.x; oa.y = bf2f(yv[1]) + xa.y;
    oa.z = bf2f(yv[2]) + xa.z; oa.w = bf2f(yv[3]) + xa.w;
    ob.x = bf2f(yv[4]) + xb.x; ob.y = bf2f(yv[5]) + xb.y;
    ob.z = bf2f(yv[6]) + xb.z; ob.w = bf2f(yv[7]) + xb.w;
    *(float4*)(outr + w) = oa;
    *(float4*)(outr + w + 4) = ob;
  }
}

// ---------------------------------------------------------------------------
extern "C" void kernel_launch(void* const* d_in, const int* in_sizes, int n_in,
                              void* d_out, int out_size, void* d_ws, size_t ws_size,
                              hipStream_t stream) {
  const float* x     = (const float*)d_in[0];
  const float* nw    = (const float*)d_in[1];
  const float* nb    = (const float*)d_in[2];
  const float* qkvw  = (const float*)d_in[3];
  const float* qkvb  = (const float*)d_in[4];
  const float* projw = (const float*)d_in[5];
  const float* projb = (const float*)d_in[6];
  const float* bt    = (const float*)d_in[7];
  const int*   ri    = (const int*)d_in[8];
  const float* am    = (const float*)d_in[9];

  unsigned short* xw   = (unsigned short*)d_ws;                        // 102,760,448 B
  unsigned short* yws  = (unsigned short*)((char*)d_ws + 102760448);   // 102,760,448 B
  float*          b2d  = (float*)((char*)d_ws + 205520896);            //      38,416 B
  unsigned short* qwbf = (unsigned short*)((char*)d_ws + 205559312);   //      98,304 B
  unsigned short* pwbf = (unsigned short*)((char*)d_ws + 205657616);   //      32,768 B
  float* out = (float*)d_out;

  k_prep<<<64,   256, 0, stream>>>(qkvw, projw, qwbf, pwbf);
  k_bias<<<38,   256, 0, stream>>>(bt, ri, b2d);
  k_ln  <<<1568, 256, 0, stream>>>(x, nw, nb, xw);
  k_attn<<<8192, 256, 0, stream>>>(xw, qwbf, qkvb, pwbf, projb, b2d, am, yws);
  k_out <<<3584, 256, 0, stream>>>(yws, x, out);
}